// Round 7
// baseline (65.633 us; speedup 1.0000x reference)
//
#include <hip/hip_runtime.h>
#include <stdint.h>

typedef unsigned short u16;
typedef __attribute__((ext_vector_type(8))) short bf16x8;
typedef __attribute__((ext_vector_type(8))) u16  u16x8;
typedef __attribute__((ext_vector_type(4))) float f32x4;

// Problem constants
static constexpr int BATCH  = 32;
static constexpr int SEQ    = 1000;
static constexpr int DIM    = 64;
static constexpr int HOUT   = 512;
static constexpr int MINLEN = 985;   // 1000 - 16 + 1
static constexpr int AROWS  = 272;   // 256-row tile + 15 window ext, rounded

// ws layout (bytes)
static constexpr size_t WF_OFF = 4u << 20;   // Wp packed bf16: 512*1024 u16 = 1 MiB
static constexpr size_t BE_OFF = 5u << 20;   // beff f32: 512

__device__ inline u16 f2bf(float f) {
  union { float f; uint32_t u; } v; v.f = f;
  uint32_t r = v.u + 0x7fffu + ((v.u >> 16) & 1u);
  return (u16)(r >> 16);
}

// ---- prep: fold W and PACK into MFMA-fragment order; beff = mean bias ----
//   packed u16 idx = ((h>>4)*32 + (k>>5))*512 + ((k>>3)&3)*128 + (h&15)*8 + (k&7)
//   -> fragment (hgrp, kt) is contiguous 1 KB; lane l reads 16B at l*8
__global__ void pe_prep(const float* __restrict__ W0, const float* __restrict__ W1,
                        const float* __restrict__ W2, const float* __restrict__ b0,
                        const float* __restrict__ b1, const float* __restrict__ b2,
                        u16* __restrict__ Wp, float* __restrict__ beff) {
  int bid = blockIdx.x;
  if (bid < 256) {
    int j  = bid * 256 + threadIdx.x;            // 0..65535: one 8-elem k-chunk
    int h  = j >> 7;
    int kc = j & 127;                            // k = kc*8 + e
    float v[8];
    const float4* w2 = (const float4*)(W2 + h * 1024 + kc * 8);
    float4 a = w2[0], c = w2[1];
    v[0]=a.x; v[1]=a.y; v[2]=a.z; v[3]=a.w; v[4]=c.x; v[5]=c.y; v[6]=c.z; v[7]=c.w;
    if (kc < 64) {
      const float4* w1 = (const float4*)(W1 + h * 512 + kc * 8);
      float4 d = w1[0], e = w1[1];
      v[0]+=d.x; v[1]+=d.y; v[2]+=d.z; v[3]+=d.w; v[4]+=e.x; v[5]+=e.y; v[6]+=e.z; v[7]+=e.w;
    }
    if (kc < 32) {
      const float4* w0 = (const float4*)(W0 + h * 256 + kc * 8);
      float4 d = w0[0], e = w0[1];
      v[0]+=d.x; v[1]+=d.y; v[2]+=d.z; v[3]+=d.w; v[4]+=e.x; v[5]+=e.y; v[6]+=e.z; v[7]+=e.w;
    }
    u16x8 o;
    #pragma unroll
    for (int e = 0; e < 8; ++e) o[e] = f2bf(v[e] * (1.0f / 3.0f));
    size_t dst = ((size_t)(h >> 4) * 32 + (kc >> 2)) * 512 + (kc & 3) * 128 + (h & 15) * 8;
    *(u16x8*)(Wp + dst) = o;
  } else {
    int h = (bid - 256) * 256 + threadIdx.x;
    if (h < HOUT) beff[h] = (b0[h] + b1[h] + b2[h]) * (1.0f / 3.0f);
  }
}

// ---- GEMM: out[b,l,h] = dot(window) + beff[h] + pos[l,h]
// Block 256x128, 4 waves (2m x 2n); wave = 128x64 -> acc[8][4]: 32 MFMA per
// phase (155-cyc issue burst = 2x R6's stall coverage per wave). BK=32, 32 kt.
// A: sliding window (271 rows) converted f32->bf16 INLINE and staged once in
// LDS (reg-staged, directly swizzled ds_write: slot8 ^= row&7 -> 2-way, free).
// B: NOT staged; packed Wp (1 MB, L2-resident) fragment loads, coalesced
// dwordx4, 1-kt-deep double buffer (bA/bB rotate via unroll-2).
// K-loop has ZERO barriers; setprio(1) wraps each 32-MFMA cluster (T5).
// VGPR ~210 < 256 cap -> 2 blocks/CU (grid 512 = exactly 2/CU, 8 waves/CU).
__global__ __launch_bounds__(256, 2) void pe_gemm(
    const float* __restrict__ x, const u16* __restrict__ Wp,
    const float* __restrict__ beff, const float* __restrict__ pos,
    float* __restrict__ out) {
  __shared__ u16 ldsA[AROWS * 64];     // 34,816 B, persistent

  const int t    = threadIdx.x;
  const int w    = t >> 6;
  const int lane = t & 63;
  const int b    = blockIdx.z;
  const int l0   = blockIdx.y * 256;
  const int n0   = blockIdx.x * 128;
  const int wr   = w >> 1;             // 0..1 -> 128-row band
  const int wc   = w & 1;              // 0..1 -> 64-col band
  const int lr   = lane & 15;
  const int g    = lane >> 4;          // 0..3

  // this wave's packed-B base: hgrps [(n0>>4)+wc*4, +4)
  const u16* Bp = Wp + ((size_t)((n0 >> 4) + wc * 4) * 32) * 512 + lane * 8;

  // ---- prologue: convert + stage A (272 rows x 64), swizzled ds_write ----
  const float* Ax = x + (size_t)b * (SEQ * DIM) + l0 * 64;
  for (int it = 0; it < 9; ++it) {
    int idx = it * 256 + t;            // 2176 = 272 rows x 8 chunks
    if (idx < AROWS * 8) {
      int row = idx >> 3, ch = idx & 7;
      u16x8 o;
      if (l0 + row < SEQ) {
        const float4* p = (const float4*)(Ax + row * 64 + ch * 8);
        float4 a = p[0], c = p[1];
        o[0] = f2bf(a.x); o[1] = f2bf(a.y); o[2] = f2bf(a.z); o[3] = f2bf(a.w);
        o[4] = f2bf(c.x); o[5] = f2bf(c.y); o[6] = f2bf(c.z); o[7] = f2bf(c.w);
      } else {
        o = (u16x8)(0);                // rows >= SEQ feed only masked outputs
      }
      int s = ch ^ (row & 7);
      *(u16x8*)&ldsA[row * 64 + s * 8] = o;
    }
  }

  bf16x8 bA[4], bB[4];
  #pragma unroll
  for (int n = 0; n < 4; ++n)
    bA[n] = *(const bf16x8*)(Bp + (size_t)(n * 32) * 512);

  __syncthreads();                     // A staged (all waves' rows visible)

  f32x4 acc[8][4] = {};
  const int rbase = wr * 128 + lr;

  #define A_READS(kt_, aF_)                                                   \
    _Pragma("unroll")                                                         \
    for (int m = 0; m < 8; ++m) {                                             \
      int r = rbase + m * 16 + ((kt_) >> 1);                                  \
      int s = ((((kt_) & 1) << 2) + g) ^ (r & 7);                             \
      aF_[m] = *(const bf16x8*)&ldsA[r * 64 + s * 8];                         \
    }
  #define B_LOADS(kt_, dst_)                                                  \
    _Pragma("unroll")                                                         \
    for (int n = 0; n < 4; ++n)                                               \
      dst_[n] = *(const bf16x8*)(Bp + (size_t)(n * 32 + (kt_)) * 512);
  #define MFMAS(aF_, bF_)                                                     \
    __builtin_amdgcn_s_setprio(1);                                            \
    _Pragma("unroll")                                                         \
    for (int m = 0; m < 8; ++m)                                               \
      _Pragma("unroll")                                                       \
      for (int n = 0; n < 4; ++n)                                             \
        acc[m][n] = __builtin_amdgcn_mfma_f32_16x16x32_bf16(aF_[m], bF_[n],   \
                                                            acc[m][n], 0, 0, 0); \
    __builtin_amdgcn_s_setprio(0);

  for (int kt = 0; kt < 32; kt += 2) {
    bf16x8 aF[8];
    if (kt + 1 < 32) { B_LOADS(kt + 1, bB); }
    A_READS(kt, aF);
    MFMAS(aF, bA);
    if (kt + 2 < 32) { B_LOADS(kt + 2, bA); }
    A_READS(kt + 1, aF);
    MFMAS(aF, bB);
  }
  #undef A_READS
  #undef B_LOADS
  #undef MFMAS

  // ---- epilogue: D row=(lane>>4)*4+r, col=lane&15 (m89) ----
  #pragma unroll
  for (int n = 0; n < 4; ++n) {
    const int h  = n0 + wc * 64 + n * 16 + lr;
    const float bv = beff[h];
    #pragma unroll
    for (int m = 0; m < 8; ++m) {
      const int rowb = l0 + wr * 128 + m * 16 + (g << 2);
      #pragma unroll
      for (int r = 0; r < 4; ++r) {
        const int l = rowb + r;
        if (l < MINLEN) {
          out[((size_t)b * MINLEN + l) * HOUT + h] =
              acc[m][n][r] + bv + pos[(size_t)l * HOUT + h];
        }
      }
    }
  }
}

extern "C" void kernel_launch(void* const* d_in, const int* in_sizes, int n_in,
                              void* d_out, int out_size, void* d_ws, size_t ws_size,
                              hipStream_t stream) {
  const float* x   = (const float*)d_in[0];
  const float* W0  = (const float*)d_in[1];
  const float* b0  = (const float*)d_in[2];
  const float* W1  = (const float*)d_in[3];
  const float* b1  = (const float*)d_in[4];
  const float* W2  = (const float*)d_in[5];
  const float* b2  = (const float*)d_in[6];
  const float* pos = (const float*)d_in[7];
  float* out = (float*)d_out;

  char* ws  = (char*)d_ws;
  u16*  Wp  = (u16*)(ws + WF_OFF);
  float* be = (float*)(ws + BE_OFF);

  // prep: 256 fold/pack blocks + 2 bias blocks
  hipLaunchKernelGGL(pe_prep, dim3(258), dim3(256), 0, stream,
                     W0, W1, W2, b0, b1, b2, Wp, be);
  // 4 n-tiles x 4 m-tiles x 32 batch = 512 blocks = exactly 2/CU
  hipLaunchKernelGGL(pe_gemm, dim3(HOUT / 128, 4, BATCH), dim3(256), 0, stream,
                     x, Wp, be, pos, out);
}

// Round 8
// 64.156 us; speedup vs baseline: 1.0230x; 1.0230x over previous
//
#include <hip/hip_runtime.h>
#include <stdint.h>

typedef unsigned short u16;
typedef __attribute__((ext_vector_type(8))) short bf16x8;
typedef __attribute__((ext_vector_type(8))) u16  u16x8;
typedef __attribute__((ext_vector_type(4))) float f32x4;

// Problem constants
static constexpr int BATCH  = 32;
static constexpr int SEQ    = 1000;
static constexpr int DIM    = 64;
static constexpr int HOUT   = 512;
static constexpr int MINLEN = 985;   // 1000 - 16 + 1
static constexpr int AROWS  = 144;   // 128-row tile + 15 window ext + pad

// ws layout (bytes)
static constexpr size_t PB_OFF = 0;          // posb f32: 985*512 = 1.97 MB
static constexpr size_t WF_OFF = 4u << 20;   // Wp packed bf16: 512*1024 u16 = 1 MiB

__device__ inline u16 f2bf(float f) {
  union { float f; uint32_t u; } v; v.f = f;
  uint32_t r = v.u + 0x7fffu + ((v.u >> 16) & 1u);
  return (u16)(r >> 16);
}

// ---- prep ----------------------------------------------------------------
// bid <  256 : fold W and PACK into MFMA-fragment order:
//   packed u16 idx = ((h>>4)*32 + (k>>5))*512 + ((k>>3)&3)*128 + (h&15)*8 + (k&7)
//   -> fragment (hgrp, kt) is contiguous 1 KB; lane l reads 16B at l*8
// bid >= 256 : posb[l,h] = pos[l,h] + (b0[h]+b1[h]+b2[h])/3   (float4 chunks)
__global__ void pe_prep(const float* __restrict__ W0, const float* __restrict__ W1,
                        const float* __restrict__ W2, const float* __restrict__ b0,
                        const float* __restrict__ b1, const float* __restrict__ b2,
                        const float* __restrict__ pos,
                        u16* __restrict__ Wp, float* __restrict__ posb) {
  int bid = blockIdx.x;
  if (bid < 256) {
    int j  = bid * 256 + threadIdx.x;            // 0..65535: one 8-elem k-chunk
    int h  = j >> 7;
    int kc = j & 127;                            // k = kc*8 + e
    float v[8];
    const float4* w2 = (const float4*)(W2 + h * 1024 + kc * 8);
    float4 a = w2[0], c = w2[1];
    v[0]=a.x; v[1]=a.y; v[2]=a.z; v[3]=a.w; v[4]=c.x; v[5]=c.y; v[6]=c.z; v[7]=c.w;
    if (kc < 64) {
      const float4* w1 = (const float4*)(W1 + h * 512 + kc * 8);
      float4 d = w1[0], e = w1[1];
      v[0]+=d.x; v[1]+=d.y; v[2]+=d.z; v[3]+=d.w; v[4]+=e.x; v[5]+=e.y; v[6]+=e.z; v[7]+=e.w;
    }
    if (kc < 32) {
      const float4* w0 = (const float4*)(W0 + h * 256 + kc * 8);
      float4 d = w0[0], e = w0[1];
      v[0]+=d.x; v[1]+=d.y; v[2]+=d.z; v[3]+=d.w; v[4]+=e.x; v[5]+=e.y; v[6]+=e.z; v[7]+=e.w;
    }
    u16x8 o;
    #pragma unroll
    for (int e = 0; e < 8; ++e) o[e] = f2bf(v[e] * (1.0f / 3.0f));
    size_t dst = ((size_t)(h >> 4) * 32 + (kc >> 2)) * 512 + (kc & 3) * 128 + (h & 15) * 8;
    *(u16x8*)(Wp + dst) = o;
  } else {
    int idx = (bid - 256) * 256 + threadIdx.x;   // float4 index into posb
    if (idx < MINLEN * (HOUT / 4)) {
      int l  = idx >> 7;                         // 128 float4 per row
      int h4 = idx & 127;
      float4 p  = ((const float4*)pos)[(size_t)l * 128 + h4];
      float4 a0 = ((const float4*)b0)[h4];
      float4 a1 = ((const float4*)b1)[h4];
      float4 a2 = ((const float4*)b2)[h4];
      float4 o;
      o.x = p.x + (a0.x + a1.x + a2.x) * (1.0f / 3.0f);
      o.y = p.y + (a0.y + a1.y + a2.y) * (1.0f / 3.0f);
      o.z = p.z + (a0.z + a1.z + a2.z) * (1.0f / 3.0f);
      o.w = p.w + (a0.w + a1.w + a2.w) * (1.0f / 3.0f);
      ((float4*)posb)[idx] = o;
    }
  }
}

// ---- GEMM: out[b,l,h] = dot(window) + posb[l,h]
// R6 winning geometry: 128x128 tile, 4 waves (2m x 2n), wave 64x64 ->
// acc[4][4], BK=32, 32 kt, ZERO barriers in K-loop.
// A: sliding window (144 rows) converted f32->bf16 INLINE, staged once in LDS
//    (directly swizzled ds_write: slot8 ^= row&7 -> 2-way, free).
// B: not staged; packed Wp (1 MB, L2-resident) coalesced dwordx4 fragment
//    loads, 1-kt-deep register double buffer.
// XCD swizzle (bijective, 1024%8==0): each XCD gets 4 complete (batch) groups
//    -> A-panel + out lines localized to one L2; per-XCD set ~4 MB.
// LDS 18.4 KB + 128 unified regs -> 4 blocks/CU (16 waves/CU).
__global__ __launch_bounds__(256, 4) void pe_gemm(
    const float* __restrict__ x, const u16* __restrict__ Wp,
    const float* __restrict__ posb, float* __restrict__ out) {
  __shared__ u16 ldsA[AROWS * 64];     // 18,432 B, persistent

  const int t    = threadIdx.x;
  const int w    = t >> 6;
  const int lane = t & 63;

  // XCD swizzle: 1024 blocks -> XCD gets 128 consecutive logical ids
  const int sw = (blockIdx.x & 7) * 128 + (blockIdx.x >> 3);
  const int n0 = (sw & 3) * 128;       // 4 n-tiles
  const int l0 = ((sw >> 2) & 7) * 128; // 8 m-tiles
  const int b  = sw >> 5;              // 32 batches

  const int wr   = w >> 1;             // 0..1 -> 64-row band
  const int wc   = w & 1;              // 0..1 -> 64-col band
  const int lr   = lane & 15;
  const int g    = lane >> 4;          // 0..3

  // this wave's packed-B base: hgrps [(n0>>4)+wc*4, +4)
  const u16* Bp = Wp + ((size_t)((n0 >> 4) + wc * 4) * 32) * 512 + lane * 8;

  // ---- prologue: inline f32->bf16 convert + swizzled stage of A ----
  const float* Ax = x + (size_t)b * (SEQ * DIM) + (size_t)l0 * 64;
  #pragma unroll
  for (int it = 0; it < 5; ++it) {
    int idx = it * 256 + t;            // 1152 = 144 rows x 8 chunks
    if (idx < AROWS * 8) {
      int row = idx >> 3, ch = idx & 7;
      u16x8 o;
      if (l0 + row < SEQ) {
        const float4* p = (const float4*)(Ax + row * 64 + ch * 8);
        float4 a = p[0], c = p[1];
        o[0] = f2bf(a.x); o[1] = f2bf(a.y); o[2] = f2bf(a.z); o[3] = f2bf(a.w);
        o[4] = f2bf(c.x); o[5] = f2bf(c.y); o[6] = f2bf(c.z); o[7] = f2bf(c.w);
      } else {
        o = (u16x8)(0);                // rows >= SEQ feed only masked outputs
      }
      *(u16x8*)&ldsA[row * 64 + (ch ^ (row & 7)) * 8] = o;
    }
  }

  bf16x8 bA[4], bB[4];
  #pragma unroll
  for (int n = 0; n < 4; ++n)
    bA[n] = *(const bf16x8*)(Bp + (size_t)(n * 32) * 512);

  __syncthreads();                     // A staged (all waves' rows visible)

  f32x4 acc[4][4] = {};
  const int rbase = wr * 64 + lr;

  #define A_READS(kt_, aF_)                                                   \
    _Pragma("unroll")                                                         \
    for (int m = 0; m < 4; ++m) {                                             \
      int r = rbase + m * 16 + ((kt_) >> 1);                                  \
      int s = ((((kt_) & 1) << 2) + g) ^ (r & 7);                             \
      aF_[m] = *(const bf16x8*)&ldsA[r * 64 + s * 8];                         \
    }
  #define B_LOADS(kt_, dst_)                                                  \
    _Pragma("unroll")                                                         \
    for (int n = 0; n < 4; ++n)                                               \
      dst_[n] = *(const bf16x8*)(Bp + (size_t)(n * 32 + (kt_)) * 512);
  #define MFMAS(aF_, bF_)                                                     \
    __builtin_amdgcn_s_setprio(1);                                            \
    _Pragma("unroll")                                                         \
    for (int m = 0; m < 4; ++m)                                               \
      _Pragma("unroll")                                                       \
      for (int n = 0; n < 4; ++n)                                             \
        acc[m][n] = __builtin_amdgcn_mfma_f32_16x16x32_bf16(aF_[m], bF_[n],   \
                                                            acc[m][n], 0, 0, 0); \
    __builtin_amdgcn_s_setprio(0);

  for (int kt = 0; kt < 32; kt += 2) {
    bf16x8 aF[8];
    if (kt + 1 < 32) { B_LOADS(kt + 1, bB); }
    A_READS(kt, aF);
    MFMAS(aF, bA);
    if (kt + 2 < 32) { B_LOADS(kt + 2, bA); }
    A_READS(kt + 1, aF);
    MFMAS(aF, bB);
  }
  #undef A_READS
  #undef B_LOADS
  #undef MFMAS

  // ---- epilogue: D row=(lane>>4)*4+r, col=lane&15 (m89); posb fused ----
  #pragma unroll
  for (int n = 0; n < 4; ++n) {
    const int h = n0 + wc * 64 + n * 16 + lr;
    #pragma unroll
    for (int m = 0; m < 4; ++m) {
      const int rowb = l0 + wr * 64 + m * 16 + (g << 2);
      #pragma unroll
      for (int r = 0; r < 4; ++r) {
        const int l = rowb + r;
        if (l < MINLEN) {
          out[((size_t)b * MINLEN + l) * HOUT + h] =
              acc[m][n][r] + posb[(size_t)l * HOUT + h];
        }
      }
    }
  }
}

extern "C" void kernel_launch(void* const* d_in, const int* in_sizes, int n_in,
                              void* d_out, int out_size, void* d_ws, size_t ws_size,
                              hipStream_t stream) {
  const float* x   = (const float*)d_in[0];
  const float* W0  = (const float*)d_in[1];
  const float* b0  = (const float*)d_in[2];
  const float* W1  = (const float*)d_in[3];
  const float* b1  = (const float*)d_in[4];
  const float* W2  = (const float*)d_in[5];
  const float* b2  = (const float*)d_in[6];
  const float* pos = (const float*)d_in[7];
  float* out = (float*)d_out;

  char*  ws   = (char*)d_ws;
  float* posb = (float*)(ws + PB_OFF);
  u16*   Wp   = (u16*)(ws + WF_OFF);

  // prep: 256 fold/pack blocks + 493 posb blocks
  hipLaunchKernelGGL(pe_prep, dim3(256 + 493), dim3(256), 0, stream,
                     W0, W1, W2, b0, b1, b2, pos, Wp, posb);
  // 4 n-tiles x 8 m-tiles x 32 batch = 1024 blocks = exactly 4/CU
  hipLaunchKernelGGL(pe_gemm, dim3(1024), dim3(256), 0, stream,
                     x, Wp, posb, out);
}